// Round 6
// baseline (204.072 us; speedup 1.0000x reference)
//
#include <hip/hip_runtime.h>

// GlobalLocalPool: B=16, T=4096, H=512, fp32 in/out.
// out[b, 0:H]   = sum_{t < len[b]}  x[b,t,:] / max(len[b],1)
// out[b, H:2H]  = sum_{mask[b,t]}   x[b,t,:] / max(popcount(mask[b]),1)
// (span-compaction in the reference == plain masked mean; mask arrives as int32.)
//
// R5 lesson: per-wave software pipelining was neutral — the limiter is
// machine-level TLP, not per-wave MLP. 1024 blocks = 8 waves/CU left the
// memory pipe idle during batch drains. This round: 4096 blocks x 256 thr
// (16K waves), one 8-wide float4 batch per thread, then exit — the CP keeps
// ~32 waves/CU resident, ~256 KB in flight per CU.

constexpr int Bc = 16;
constexpr int Tc = 4096;
constexpr int Hc = 512;
constexpr int H4 = Hc / 4;             // 128 float4 per token
constexpr int CHUNK   = 16;            // tokens per stage-1 block
constexpr int NCHUNK  = Tc / CHUNK;    // 256 chunks per batch row
constexpr int NBLK    = Bc * NCHUNK;   // 4096 stage-1 blocks
constexpr int NROW    = NBLK * 2;      // 8192 partial rows (2 parities/block)
constexpr int ROWS_PB = NROW / Bc;     // 512 partial rows per b
constexpr int G2      = 8;             // stage-2 groups per b
constexpr int R2ROWS  = ROWS_PB / G2;  // 64 rows per stage-2 block

// ---------------- stage 1: one register batch per thread ----------------
// 256 threads: lane = tid&127 (float4 column), par = tid>>7 (token parity).
// Thread loads 8 float4s (tokens t0+par, t0+par+2, ..., t0+par+14).
__global__ __launch_bounds__(256) void glp_partial(
    const float* __restrict__ x,
    const int* __restrict__ lengths,
    const int* __restrict__ mask,   // int32 0/1
    float* __restrict__ pg,         // [NROW][Hc]
    float* __restrict__ pl,         // [NROW][Hc]
    int*   __restrict__ pcnt)       // [NROW]
{
    const int blk  = blockIdx.x;
    const int b    = blk >> 8;              // / NCHUNK
    const int c    = blk & (NCHUNK - 1);
    const int t0   = c * CHUNK;
    const int lane = threadIdx.x & 127;
    const int par  = threadIdx.x >> 7;      // wave-uniform
    const int len  = lengths[b];

    const float4* __restrict__ xb =
        (const float4*)x + ((size_t)b * Tc + t0 + par) * H4 + lane;
    const int* __restrict__ mb = mask + (size_t)b * Tc + t0 + par; // uniform/wave

    float4 v[8]; int m[8];
    #pragma unroll
    for (int j = 0; j < 8; ++j) {           // 8 back-to-back 16B loads
        v[j] = xb[(size_t)(2 * j) * H4];
        m[j] = mb[2 * j];                   // wave-uniform -> s_load
    }

    float4 g = make_float4(0.f, 0.f, 0.f, 0.f);
    float4 l = make_float4(0.f, 0.f, 0.f, 0.f);
    int mc = 0;
    #pragma unroll
    for (int j = 0; j < 8; ++j) {
        const float wg = (t0 + par + 2 * j < len) ? 1.f : 0.f;
        const float wl = m[j] ? 1.f : 0.f;
        g.x = fmaf(v[j].x, wg, g.x); g.y = fmaf(v[j].y, wg, g.y);
        g.z = fmaf(v[j].z, wg, g.z); g.w = fmaf(v[j].w, wg, g.w);
        l.x = fmaf(v[j].x, wl, l.x); l.y = fmaf(v[j].y, wl, l.y);
        l.z = fmaf(v[j].z, wl, l.z); l.w = fmaf(v[j].w, wl, l.w);
        mc += (m[j] != 0);
    }

    const int row = blk * 2 + par;
    ((float4*)(pg + (size_t)row * Hc))[lane] = g;   // 2 KB coalesced
    ((float4*)(pl + (size_t)row * Hc))[lane] = l;
    if (lane == 0) pcnt[row] = mc;                  // mask uniform across lanes
}

// ---------------- stage 2: 8192 rows -> 128 rows ----------------
__global__ __launch_bounds__(128) void glp_reduce1(
    const float* __restrict__ pg, const float* __restrict__ pl,
    const int* __restrict__ pcnt,
    float* __restrict__ qg, float* __restrict__ ql, int* __restrict__ qcnt)
{
    const int blk  = blockIdx.x;           // b*G2 + grp
    const int r0   = blk * R2ROWS;         // rows are laid out b-major already
    const int lane = threadIdx.x;
    const float4* pg4 = (const float4*)pg + (size_t)r0 * H4 + lane;
    const float4* pl4 = (const float4*)pl + (size_t)r0 * H4 + lane;

    float4 gs = make_float4(0.f, 0.f, 0.f, 0.f);
    float4 ls = make_float4(0.f, 0.f, 0.f, 0.f);
    for (int r = 0; r < R2ROWS; r += 8) {
        float4 a[8], d[8];
        #pragma unroll
        for (int j = 0; j < 8; ++j) {
            a[j] = pg4[(size_t)(r + j) * H4];
            d[j] = pl4[(size_t)(r + j) * H4];
        }
        #pragma unroll
        for (int j = 0; j < 8; ++j) {
            gs.x += a[j].x; gs.y += a[j].y; gs.z += a[j].z; gs.w += a[j].w;
            ls.x += d[j].x; ls.y += d[j].y; ls.z += d[j].z; ls.w += d[j].w;
        }
    }
    ((float4*)(qg + (size_t)blk * Hc))[lane] = gs;
    ((float4*)(ql + (size_t)blk * Hc))[lane] = ls;
    if (lane == 0) {
        int mc = 0;
        for (int r = 0; r < R2ROWS; ++r) mc += pcnt[r0 + r];  // uniform s_loads
        qcnt[blk] = mc;
    }
}

// ---------------- stage 3: 128 rows -> out [B, 2H] ----------------
__global__ __launch_bounds__(128) void glp_reduce2(
    const float* __restrict__ qg, const float* __restrict__ ql,
    const int* __restrict__ qcnt, const int* __restrict__ lengths,
    float* __restrict__ out)
{
    const int b    = blockIdx.x;
    const int lane = threadIdx.x;
    float4 gs = make_float4(0.f, 0.f, 0.f, 0.f);
    float4 ls = make_float4(0.f, 0.f, 0.f, 0.f);
    #pragma unroll
    for (int k = 0; k < G2; ++k) {
        float4 a = ((const float4*)(qg + (size_t)(b * G2 + k) * Hc))[lane];
        float4 d = ((const float4*)(ql + (size_t)(b * G2 + k) * Hc))[lane];
        gs.x += a.x; gs.y += a.y; gs.z += a.z; gs.w += a.w;
        ls.x += d.x; ls.y += d.y; ls.z += d.z; ls.w += d.w;
    }
    int cnt = 0;
    #pragma unroll
    for (int k = 0; k < G2; ++k) cnt += qcnt[b * G2 + k];  // uniform s_loads
    const float invl = 1.f / (float)max(lengths[b], 1);
    const float invc = 1.f / (float)max(cnt, 1);
    gs.x *= invl; gs.y *= invl; gs.z *= invl; gs.w *= invl;
    ls.x *= invc; ls.y *= invc; ls.z *= invc; ls.w *= invc;
    ((float4*)(out + (size_t)b * 2 * Hc))[lane]      = gs;
    ((float4*)(out + (size_t)b * 2 * Hc + Hc))[lane] = ls;
}

// ---------------- fallback (ws too small): proven atomic path ----------------
__global__ __launch_bounds__(128) void glp_partial_atomic(
    const float* __restrict__ x, const int* __restrict__ lengths,
    const int* __restrict__ mask,
    float* __restrict__ gsum, float* __restrict__ lsum, int* __restrict__ cnt)
{
    const int blk  = blockIdx.x;          // Bc*64 blocks, 64-token chunks
    const int b    = blk >> 6;
    const int c    = blk & 63;
    const int t0   = c * 64;
    const int lane = threadIdx.x;
    const int len  = lengths[b];
    const float4* __restrict__ xb =
        (const float4*)x + ((size_t)b * Tc + t0) * H4 + lane;
    const int* __restrict__ mb = mask + (size_t)b * Tc + t0;

    float4 g = make_float4(0.f, 0.f, 0.f, 0.f);
    float4 l = make_float4(0.f, 0.f, 0.f, 0.f);
    int mc = 0;
    for (int ii = 0; ii < 64; ii += 8) {
        float4 v[8]; int m[8];
        #pragma unroll
        for (int j = 0; j < 8; ++j) { v[j] = xb[(size_t)(ii + j) * H4]; m[j] = mb[ii + j]; }
        #pragma unroll
        for (int j = 0; j < 8; ++j) {
            const float wg = (t0 + ii + j < len) ? 1.f : 0.f;
            const float wl = m[j] ? 1.f : 0.f;
            g.x = fmaf(v[j].x, wg, g.x); g.y = fmaf(v[j].y, wg, g.y);
            g.z = fmaf(v[j].z, wg, g.z); g.w = fmaf(v[j].w, wg, g.w);
            l.x = fmaf(v[j].x, wl, l.x); l.y = fmaf(v[j].y, wl, l.y);
            l.z = fmaf(v[j].z, wl, l.z); l.w = fmaf(v[j].w, wl, l.w);
            mc += (m[j] != 0);
        }
    }
    float* gp = gsum + b * Hc + lane * 4;
    float* lp = lsum + b * Hc + lane * 4;
    atomicAdd(gp + 0, g.x); atomicAdd(gp + 1, g.y);
    atomicAdd(gp + 2, g.z); atomicAdd(gp + 3, g.w);
    atomicAdd(lp + 0, l.x); atomicAdd(lp + 1, l.y);
    atomicAdd(lp + 2, l.z); atomicAdd(lp + 3, l.w);
    if (lane == 0) atomicAdd(cnt + b, mc);
}

__global__ __launch_bounds__(512) void glp_finalize(
    const float* __restrict__ gsum, const float* __restrict__ lsum,
    const int* __restrict__ cnt, const int* __restrict__ lengths,
    float* __restrict__ out)
{
    const int b = blockIdx.x;
    const int h = threadIdx.x;
    out[b * 2 * Hc + h]      = gsum[b * Hc + h] / (float)max(lengths[b], 1);
    out[b * 2 * Hc + Hc + h] = lsum[b * Hc + h] / (float)max(cnt[b], 1);
}

extern "C" void kernel_launch(void* const* d_in, const int* in_sizes, int n_in,
                              void* d_out, int out_size, void* d_ws, size_t ws_size,
                              hipStream_t stream) {
    const float* x     = (const float*)d_in[0];
    const int* lengths = (const int*)d_in[1];
    const int* mask    = (const int*)d_in[2];   // bool promoted to int32 by harness
    float* out = (float*)d_out;

    const size_t npg   = (size_t)NROW * Hc;           // floats
    const size_t nq    = (size_t)Bc * G2 * Hc;        // floats
    const size_t need  = (2 * npg + 2 * nq) * sizeof(float)
                       + (NROW + Bc * G2) * sizeof(int);
    if (ws_size >= need) {
        float* pg   = (float*)d_ws;
        float* pl   = pg + npg;
        float* qg   = pl + npg;
        float* ql   = qg + nq;
        int*   pcnt = (int*)(ql + nq);
        int*   qcnt = pcnt + NROW;
        glp_partial<<<NBLK, 256, 0, stream>>>(x, lengths, mask, pg, pl, pcnt);
        glp_reduce1<<<Bc * G2, 128, 0, stream>>>(pg, pl, pcnt, qg, ql, qcnt);
        glp_reduce2<<<Bc, 128, 0, stream>>>(qg, ql, qcnt, lengths, out);
    } else {
        float* gsum = (float*)d_ws;
        float* lsum = gsum + Bc * Hc;
        int*   cnt  = (int*)(lsum + Bc * Hc);
        const size_t zb = (size_t)(2 * Bc * Hc) * sizeof(float) + Bc * sizeof(int);
        hipMemsetAsync(d_ws, 0, zb, stream);
        glp_partial_atomic<<<Bc * 64, 128, 0, stream>>>(x, lengths, mask, gsum, lsum, cnt);
        glp_finalize<<<Bc, Hc, 0, stream>>>(gsum, lsum, cnt, lengths, out);
    }
}

// Round 7
// 193.798 us; speedup vs baseline: 1.0530x; 1.0530x over previous
//
#include <hip/hip_runtime.h>

// GlobalLocalPool: B=16, T=4096, H=512, fp32 in/out.
// out[b, 0:H]   = sum_{t < len[b]}  x[b,t,:] / max(len[b],1)
// out[b, H:2H]  = sum_{mask[b,t]}   x[b,t,:] / max(popcount(mask[b]),1)
// (span-compaction in the reference == plain masked mean; mask arrives as int32.)
//
// R6 lesson: TLP alone didn't help (R6 = R4 despite 8x the waves) and extra
// partial traffic hurts. This round combines full occupancy (2048 blocks x
// 256 thr = 32 waves/CU) with minimal partial traffic (one 2 KB row per
// block via LDS parity-combine, 8 MB total) and one fewer launch.

constexpr int Bc = 16;
constexpr int Tc = 4096;
constexpr int Hc = 512;
constexpr int H4 = Hc / 4;             // 128 float4 per token
constexpr int CPB    = 128;            // chunk-columns per batch row
constexpr int NBLK   = Bc * CPB;       // 2048 stage-1 blocks
constexpr int ROWS_PB = CPB;           // 128 partial rows per b
constexpr int KITER  = 16;             // tokens per thread (2 batches of 8)

// ---------------- stage 1 ----------------
// Block (b,c): 256 threads; lane = tid&127 (float4 column), par = tid>>7.
// Thread handles tokens t = 2c + par + 256k, k=0..15 (all uniform per wave).
__global__ __launch_bounds__(256) void glp_partial(
    const float* __restrict__ x,
    const int* __restrict__ lengths,
    const int* __restrict__ mask,   // int32 0/1
    float* __restrict__ pg,         // [NBLK][Hc]
    float* __restrict__ pl,         // [NBLK][Hc]
    int*   __restrict__ pcnt)       // [NBLK]
{
    const int blk  = blockIdx.x;
    const int b    = blk >> 7;              // / CPB
    const int c    = blk & (CPB - 1);
    const int lane = threadIdx.x & 127;
    const int par  = __builtin_amdgcn_readfirstlane(threadIdx.x >> 7); // scalar
    const int tbase = 2 * c + par;          // uniform per wave
    const int len  = lengths[b];

    const float4* __restrict__ xb =
        (const float4*)x + ((size_t)b * Tc + tbase) * H4 + lane;
    const int* __restrict__ mrow = mask + (size_t)b * Tc + tbase;  // uniform

    float4 g = make_float4(0.f, 0.f, 0.f, 0.f);
    float4 l = make_float4(0.f, 0.f, 0.f, 0.f);
    int mc = 0;

    #pragma unroll
    for (int half = 0; half < 2; ++half) {
        float4 v[8]; int m[8];
        #pragma unroll
        for (int j = 0; j < 8; ++j) {           // 8 back-to-back 16B loads
            const int k = half * 8 + j;
            v[j] = xb[(size_t)k * 256 * H4];    // token stride 256
            m[j] = mrow[k * 256];               // uniform -> scalar load
        }
        #pragma unroll
        for (int j = 0; j < 8; ++j) {
            const int k = half * 8 + j;
            const int t = tbase + 256 * k;
            const float wg = (t < len) ? 1.f : 0.f;
            const float wl = m[j] ? 1.f : 0.f;
            g.x = fmaf(v[j].x, wg, g.x); g.y = fmaf(v[j].y, wg, g.y);
            g.z = fmaf(v[j].z, wg, g.z); g.w = fmaf(v[j].w, wg, g.w);
            l.x = fmaf(v[j].x, wl, l.x); l.y = fmaf(v[j].y, wl, l.y);
            l.z = fmaf(v[j].z, wl, l.z); l.w = fmaf(v[j].w, wl, l.w);
            mc += (m[j] != 0);
        }
    }

    // combine the two parities through LDS -> one partial row per block
    __shared__ float4 sg[128];
    __shared__ float4 sl[128];
    __shared__ int smc[2];
    if (par == 1) { sg[lane] = g; sl[lane] = l; }
    if (threadIdx.x == 0)   smc[0] = mc;   // mask uniform across a parity's lanes
    if (threadIdx.x == 128) smc[1] = mc;
    __syncthreads();
    if (par == 0) {
        const float4 og = sg[lane], ol = sl[lane];
        g.x += og.x; g.y += og.y; g.z += og.z; g.w += og.w;
        l.x += ol.x; l.y += ol.y; l.z += ol.z; l.w += ol.w;
        ((float4*)(pg + (size_t)blk * Hc))[lane] = g;   // 2 KB coalesced
        ((float4*)(pl + (size_t)blk * Hc))[lane] = l;
    }
    if (threadIdx.x == 0) pcnt[blk] = smc[0] + smc[1];
}

// ---------------- stage 2: 2048 rows -> out [B, 2H] ----------------
// Grid 128 blocks (8 per b), 128 threads. Block (b,o) covers float4 columns
// [o*16, o*16+16); thread (col = o*16 + tid&15, rg = tid>>4) sums rows
// rg+8j over j=0..15; LDS-reduce the 8 row-groups; 16 threads emit output.
__global__ __launch_bounds__(128) void glp_reduce(
    const float* __restrict__ pg, const float* __restrict__ pl,
    const int* __restrict__ pcnt, const int* __restrict__ lengths,
    float* __restrict__ out)
{
    const int b   = blockIdx.x >> 3;
    const int o   = blockIdx.x & 7;
    const int col = o * 16 + (threadIdx.x & 15);   // float4 column in [0,128)
    const int rg  = threadIdx.x >> 4;              // 0..7

    const float4* pg4 = (const float4*)pg;
    const float4* pl4 = (const float4*)pl;

    float4 gs = make_float4(0.f, 0.f, 0.f, 0.f);
    float4 ls = make_float4(0.f, 0.f, 0.f, 0.f);
    #pragma unroll
    for (int half = 0; half < 2; ++half) {
        float4 a[8], d[8];
        #pragma unroll
        for (int j = 0; j < 8; ++j) {
            const int r = b * ROWS_PB + rg + 8 * (half * 8 + j);
            a[j] = pg4[(size_t)r * H4 + col];
            d[j] = pl4[(size_t)r * H4 + col];
        }
        #pragma unroll
        for (int j = 0; j < 8; ++j) {
            gs.x += a[j].x; gs.y += a[j].y; gs.z += a[j].z; gs.w += a[j].w;
            ls.x += d[j].x; ls.y += d[j].y; ls.z += d[j].z; ls.w += d[j].w;
        }
    }

    __shared__ float4 lg[128], ll[128];
    lg[threadIdx.x] = gs; ll[threadIdx.x] = ls;
    __syncthreads();
    if (rg == 0) {
        #pragma unroll
        for (int j = 1; j < 8; ++j) {
            const float4 a = lg[j * 16 + (threadIdx.x & 15)];
            const float4 d = ll[j * 16 + (threadIdx.x & 15)];
            gs.x += a.x; gs.y += a.y; gs.z += a.z; gs.w += a.w;
            ls.x += d.x; ls.y += d.y; ls.z += d.z; ls.w += d.w;
        }
        int cnt = 0;
        for (int i = 0; i < ROWS_PB; ++i) cnt += pcnt[b * ROWS_PB + i]; // uniform
        const float invl = 1.f / (float)max(lengths[b], 1);
        const float invc = 1.f / (float)max(cnt, 1);
        gs.x *= invl; gs.y *= invl; gs.z *= invl; gs.w *= invl;
        ls.x *= invc; ls.y *= invc; ls.z *= invc; ls.w *= invc;
        ((float4*)out)[b * 256 + col]       = gs;   // out row = 1024 floats
        ((float4*)out)[b * 256 + 128 + col] = ls;
    }
}

// ---------------- fallback (ws too small): proven atomic path ----------------
__global__ __launch_bounds__(128) void glp_partial_atomic(
    const float* __restrict__ x, const int* __restrict__ lengths,
    const int* __restrict__ mask,
    float* __restrict__ gsum, float* __restrict__ lsum, int* __restrict__ cnt)
{
    const int blk  = blockIdx.x;
    const int b    = blk >> 6;
    const int c    = blk & 63;
    const int t0   = c * 64;
    const int lane = threadIdx.x;
    const int len  = lengths[b];
    const float4* __restrict__ xb =
        (const float4*)x + ((size_t)b * Tc + t0) * H4 + lane;
    const int* __restrict__ mb = mask + (size_t)b * Tc + t0;

    float4 g = make_float4(0.f, 0.f, 0.f, 0.f);
    float4 l = make_float4(0.f, 0.f, 0.f, 0.f);
    int mc = 0;
    for (int ii = 0; ii < 64; ii += 8) {
        float4 v[8]; int m[8];
        #pragma unroll
        for (int j = 0; j < 8; ++j) { v[j] = xb[(size_t)(ii + j) * H4]; m[j] = mb[ii + j]; }
        #pragma unroll
        for (int j = 0; j < 8; ++j) {
            const float wg = (t0 + ii + j < len) ? 1.f : 0.f;
            const float wl = m[j] ? 1.f : 0.f;
            g.x = fmaf(v[j].x, wg, g.x); g.y = fmaf(v[j].y, wg, g.y);
            g.z = fmaf(v[j].z, wg, g.z); g.w = fmaf(v[j].w, wg, g.w);
            l.x = fmaf(v[j].x, wl, l.x); l.y = fmaf(v[j].y, wl, l.y);
            l.z = fmaf(v[j].z, wl, l.z); l.w = fmaf(v[j].w, wl, l.w);
            mc += (m[j] != 0);
        }
    }
    float* gp = gsum + b * Hc + lane * 4;
    float* lp = lsum + b * Hc + lane * 4;
    atomicAdd(gp + 0, g.x); atomicAdd(gp + 1, g.y);
    atomicAdd(gp + 2, g.z); atomicAdd(gp + 3, g.w);
    atomicAdd(lp + 0, l.x); atomicAdd(lp + 1, l.y);
    atomicAdd(lp + 2, l.z); atomicAdd(lp + 3, l.w);
    if (lane == 0) atomicAdd(cnt + b, mc);
}

__global__ __launch_bounds__(512) void glp_finalize(
    const float* __restrict__ gsum, const float* __restrict__ lsum,
    const int* __restrict__ cnt, const int* __restrict__ lengths,
    float* __restrict__ out)
{
    const int b = blockIdx.x;
    const int h = threadIdx.x;
    out[b * 2 * Hc + h]      = gsum[b * Hc + h] / (float)max(lengths[b], 1);
    out[b * 2 * Hc + Hc + h] = lsum[b * Hc + h] / (float)max(cnt[b], 1);
}

extern "C" void kernel_launch(void* const* d_in, const int* in_sizes, int n_in,
                              void* d_out, int out_size, void* d_ws, size_t ws_size,
                              hipStream_t stream) {
    const float* x     = (const float*)d_in[0];
    const int* lengths = (const int*)d_in[1];
    const int* mask    = (const int*)d_in[2];   // bool promoted to int32 by harness
    float* out = (float*)d_out;

    const size_t npg  = (size_t)NBLK * Hc;  // floats per partial array
    const size_t need = 2 * npg * sizeof(float) + NBLK * sizeof(int);
    if (ws_size >= need) {
        float* pg   = (float*)d_ws;
        float* pl   = pg + npg;
        int*   pcnt = (int*)(pl + npg);
        glp_partial<<<NBLK, 256, 0, stream>>>(x, lengths, mask, pg, pl, pcnt);
        glp_reduce<<<Bc * 8, 128, 0, stream>>>(pg, pl, pcnt, lengths, out);
    } else {
        float* gsum = (float*)d_ws;
        float* lsum = gsum + Bc * Hc;
        int*   cnt  = (int*)(lsum + Bc * Hc);
        const size_t zb = (size_t)(2 * Bc * Hc) * sizeof(float) + Bc * sizeof(int);
        hipMemsetAsync(d_ws, 0, zb, stream);
        glp_partial_atomic<<<Bc * 64, 128, 0, stream>>>(x, lengths, mask, gsum, lsum, cnt);
        glp_finalize<<<Bc, Hc, 0, stream>>>(gsum, lsum, cnt, lengths, out);
    }
}

// Round 8
// 190.555 us; speedup vs baseline: 1.0709x; 1.0170x over previous
//
#include <hip/hip_runtime.h>

// GlobalLocalPool: B=16, T=4096, H=512, fp32 in/out.
// out[b, 0:H]   = sum_{t < len[b]}  x[b,t,:] / max(len[b],1)
// out[b, H:2H]  = sum_{mask[b,t]}   x[b,t,:] / max(popcount(mask[b]),1)
//
// R7 lesson: read streaming pins at ~2.9 TB/s across all structures ==
// per-CU outstanding-cacheline ceiling (~64 MSHR x 64B / 375ns x 256 CU).
// Only fewer line requests help. This round: dead tokens (t>=len && !mask,
// ~25%) get their load ADDRESS clamped to the batch anchor row via cndmask
// (no branch, MLP intact) -> dup lines merge in L1/MSHR, ~25% fewer line
// requests. Weights are 0 for dead tokens so the loaded value is ignored.

constexpr int Bc = 16;
constexpr int Tc = 4096;
constexpr int Hc = 512;
constexpr int H4 = Hc / 4;             // 128 float4 per token
constexpr int CPB    = 128;            // chunk-columns per batch row
constexpr int NBLK   = Bc * CPB;       // 2048 stage-1 blocks
constexpr int ROWS_PB = CPB;           // 128 partial rows per b

// ---------------- stage 1 ----------------
// Block (b,c): 256 threads; lane = tid&127 (float4 column), par = tid>>7.
// Thread handles tokens t = 2c + par + 256k, k=0..15 (wave-uniform set).
__global__ __launch_bounds__(256) void glp_partial(
    const float* __restrict__ x,
    const int* __restrict__ lengths,
    const int* __restrict__ mask,   // int32 0/1
    float* __restrict__ pg,         // [NBLK][Hc]
    float* __restrict__ pl,         // [NBLK][Hc]
    int*   __restrict__ pcnt)       // [NBLK]
{
    const int blk  = blockIdx.x;
    const int b    = blk >> 7;              // / CPB
    const int c    = blk & (CPB - 1);
    const int lane = threadIdx.x & 127;
    const int par  = __builtin_amdgcn_readfirstlane(threadIdx.x >> 7); // scalar
    const int tbase = 2 * c + par;          // uniform per wave
    const int len  = lengths[b];

    const float4* __restrict__ xb =
        (const float4*)x + ((size_t)b * Tc + tbase) * H4 + lane;
    const int* __restrict__ mrow = mask + (size_t)b * Tc + tbase;  // uniform

    float4 g = make_float4(0.f, 0.f, 0.f, 0.f);
    float4 l = make_float4(0.f, 0.f, 0.f, 0.f);
    int mc = 0;

    // all 16 mask words up front (wave-uniform scalar loads, lgkm pipe)
    int m[16];
    #pragma unroll
    for (int k = 0; k < 16; ++k) m[k] = mrow[k * 256];

    #pragma unroll
    for (int half = 0; half < 2; ++half) {
        float4 v[8];
        size_t off[8];
        #pragma unroll
        for (int j = 0; j < 8; ++j) {
            const int k = half * 8 + j;
            const int t = tbase + 256 * k;
            const bool alive = (t < len) || (m[k] != 0);
            // dead token -> re-read anchor row (k=0): dup lines merge, no new
            // line request; value is multiplied by 0 below.
            off[j] = alive ? (size_t)k * 256 * H4 : (size_t)0;
        }
        #pragma unroll
        for (int j = 0; j < 8; ++j) v[j] = xb[off[j]];   // 8 back-to-back loads
        #pragma unroll
        for (int j = 0; j < 8; ++j) {
            const int k = half * 8 + j;
            const int t = tbase + 256 * k;
            const float wg = (t < len) ? 1.f : 0.f;
            const float wl = m[k] ? 1.f : 0.f;
            g.x = fmaf(v[j].x, wg, g.x); g.y = fmaf(v[j].y, wg, g.y);
            g.z = fmaf(v[j].z, wg, g.z); g.w = fmaf(v[j].w, wg, g.w);
            l.x = fmaf(v[j].x, wl, l.x); l.y = fmaf(v[j].y, wl, l.y);
            l.z = fmaf(v[j].z, wl, l.z); l.w = fmaf(v[j].w, wl, l.w);
            mc += (m[k] != 0);
        }
    }

    // combine the two parities through LDS -> one partial row per block
    __shared__ float4 sg[128];
    __shared__ float4 sl[128];
    __shared__ int smc[2];
    if (par == 1) { sg[lane] = g; sl[lane] = l; }
    if (threadIdx.x == 0)   smc[0] = mc;   // mask uniform across a parity's lanes
    if (threadIdx.x == 128) smc[1] = mc;
    __syncthreads();
    if (par == 0) {
        const float4 og = sg[lane], ol = sl[lane];
        g.x += og.x; g.y += og.y; g.z += og.z; g.w += og.w;
        l.x += ol.x; l.y += ol.y; l.z += ol.z; l.w += ol.w;
        ((float4*)(pg + (size_t)blk * Hc))[lane] = g;   // 2 KB coalesced
        ((float4*)(pl + (size_t)blk * Hc))[lane] = l;
    }
    if (threadIdx.x == 0) pcnt[blk] = smc[0] + smc[1];
}

// ---------------- stage 2: 2048 rows -> out [B, 2H] ----------------
__global__ __launch_bounds__(128) void glp_reduce(
    const float* __restrict__ pg, const float* __restrict__ pl,
    const int* __restrict__ pcnt, const int* __restrict__ lengths,
    float* __restrict__ out)
{
    const int b   = blockIdx.x >> 3;
    const int o   = blockIdx.x & 7;
    const int col = o * 16 + (threadIdx.x & 15);   // float4 column in [0,128)
    const int rg  = threadIdx.x >> 4;              // 0..7

    const float4* pg4 = (const float4*)pg;
    const float4* pl4 = (const float4*)pl;

    float4 gs = make_float4(0.f, 0.f, 0.f, 0.f);
    float4 ls = make_float4(0.f, 0.f, 0.f, 0.f);
    #pragma unroll
    for (int half = 0; half < 2; ++half) {
        float4 a[8], d[8];
        #pragma unroll
        for (int j = 0; j < 8; ++j) {
            const int r = b * ROWS_PB + rg + 8 * (half * 8 + j);
            a[j] = pg4[(size_t)r * H4 + col];
            d[j] = pl4[(size_t)r * H4 + col];
        }
        #pragma unroll
        for (int j = 0; j < 8; ++j) {
            gs.x += a[j].x; gs.y += a[j].y; gs.z += a[j].z; gs.w += a[j].w;
            ls.x += d[j].x; ls.y += d[j].y; ls.z += d[j].z; ls.w += d[j].w;
        }
    }

    __shared__ float4 lg[128], ll[128];
    lg[threadIdx.x] = gs; ll[threadIdx.x] = ls;
    __syncthreads();
    if (rg == 0) {
        #pragma unroll
        for (int j = 1; j < 8; ++j) {
            const float4 a = lg[j * 16 + (threadIdx.x & 15)];
            const float4 d = ll[j * 16 + (threadIdx.x & 15)];
            gs.x += a.x; gs.y += a.y; gs.z += a.z; gs.w += a.w;
            ls.x += d.x; ls.y += d.y; ls.z += d.z; ls.w += d.w;
        }
        int cnt = 0;
        for (int i = 0; i < ROWS_PB; ++i) cnt += pcnt[b * ROWS_PB + i]; // uniform
        const float invl = 1.f / (float)max(lengths[b], 1);
        const float invc = 1.f / (float)max(cnt, 1);
        gs.x *= invl; gs.y *= invl; gs.z *= invl; gs.w *= invl;
        ls.x *= invc; ls.y *= invc; ls.z *= invc; ls.w *= invc;
        ((float4*)out)[b * 256 + col]       = gs;   // out row = 1024 floats
        ((float4*)out)[b * 256 + 128 + col] = ls;
    }
}

// ---------------- fallback (ws too small): proven atomic path ----------------
__global__ __launch_bounds__(128) void glp_partial_atomic(
    const float* __restrict__ x, const int* __restrict__ lengths,
    const int* __restrict__ mask,
    float* __restrict__ gsum, float* __restrict__ lsum, int* __restrict__ cnt)
{
    const int blk  = blockIdx.x;
    const int b    = blk >> 6;
    const int c    = blk & 63;
    const int t0   = c * 64;
    const int lane = threadIdx.x;
    const int len  = lengths[b];
    const float4* __restrict__ xb =
        (const float4*)x + ((size_t)b * Tc + t0) * H4 + lane;
    const int* __restrict__ mb = mask + (size_t)b * Tc + t0;

    float4 g = make_float4(0.f, 0.f, 0.f, 0.f);
    float4 l = make_float4(0.f, 0.f, 0.f, 0.f);
    int mc = 0;
    for (int ii = 0; ii < 64; ii += 8) {
        float4 v[8]; int m[8];
        #pragma unroll
        for (int j = 0; j < 8; ++j) { v[j] = xb[(size_t)(ii + j) * H4]; m[j] = mb[ii + j]; }
        #pragma unroll
        for (int j = 0; j < 8; ++j) {
            const float wg = (t0 + ii + j < len) ? 1.f : 0.f;
            const float wl = m[j] ? 1.f : 0.f;
            g.x = fmaf(v[j].x, wg, g.x); g.y = fmaf(v[j].y, wg, g.y);
            g.z = fmaf(v[j].z, wg, g.z); g.w = fmaf(v[j].w, wg, g.w);
            l.x = fmaf(v[j].x, wl, l.x); l.y = fmaf(v[j].y, wl, l.y);
            l.z = fmaf(v[j].z, wl, l.z); l.w = fmaf(v[j].w, wl, l.w);
            mc += (m[j] != 0);
        }
    }
    float* gp = gsum + b * Hc + lane * 4;
    float* lp = lsum + b * Hc + lane * 4;
    atomicAdd(gp + 0, g.x); atomicAdd(gp + 1, g.y);
    atomicAdd(gp + 2, g.z); atomicAdd(gp + 3, g.w);
    atomicAdd(lp + 0, l.x); atomicAdd(lp + 1, l.y);
    atomicAdd(lp + 2, l.z); atomicAdd(lp + 3, l.w);
    if (lane == 0) atomicAdd(cnt + b, mc);
}

__global__ __launch_bounds__(512) void glp_finalize(
    const float* __restrict__ gsum, const float* __restrict__ lsum,
    const int* __restrict__ cnt, const int* __restrict__ lengths,
    float* __restrict__ out)
{
    const int b = blockIdx.x;
    const int h = threadIdx.x;
    out[b * 2 * Hc + h]      = gsum[b * Hc + h] / (float)max(lengths[b], 1);
    out[b * 2 * Hc + Hc + h] = lsum[b * Hc + h] / (float)max(cnt[b], 1);
}

extern "C" void kernel_launch(void* const* d_in, const int* in_sizes, int n_in,
                              void* d_out, int out_size, void* d_ws, size_t ws_size,
                              hipStream_t stream) {
    const float* x     = (const float*)d_in[0];
    const int* lengths = (const int*)d_in[1];
    const int* mask    = (const int*)d_in[2];   // bool promoted to int32 by harness
    float* out = (float*)d_out;

    const size_t npg  = (size_t)NBLK * Hc;  // floats per partial array
    const size_t need = 2 * npg * sizeof(float) + NBLK * sizeof(int);
    if (ws_size >= need) {
        float* pg   = (float*)d_ws;
        float* pl   = pg + npg;
        int*   pcnt = (int*)(pl + npg);
        glp_partial<<<NBLK, 256, 0, stream>>>(x, lengths, mask, pg, pl, pcnt);
        glp_reduce<<<Bc * 8, 128, 0, stream>>>(pg, pl, pcnt, lengths, out);
    } else {
        float* gsum = (float*)d_ws;
        float* lsum = gsum + Bc * Hc;
        int*   cnt  = (int*)(lsum + Bc * Hc);
        const size_t zb = (size_t)(2 * Bc * Hc) * sizeof(float) + Bc * sizeof(int);
        hipMemsetAsync(d_ws, 0, zb, stream);
        glp_partial_atomic<<<Bc * 64, 128, 0, stream>>>(x, lengths, mask, gsum, lsum, cnt);
        glp_finalize<<<Bc, Hc, 0, stream>>>(gsum, lsum, cnt, lengths, out);
    }
}

// Round 9
// 189.286 us; speedup vs baseline: 1.0781x; 1.0067x over previous
//
#include <hip/hip_runtime.h>

// GlobalLocalPool: B=16, T=4096, H=512, fp32 in/out.
// out[b, 0:H]   = sum_{t < len[b]}  x[b,t,:] / max(len[b],1)
// out[b, H:2H]  = sum_{mask[b,t]}   x[b,t,:] / max(popcount(mask[b]),1)
//
// R8 lesson: clamping dead-token loads to the k=0 anchor only merged for
// half 0 (in-flight window); half 1's anchor lines were long drained and
// L1-evicted -> full re-requests. Fix: clamp to the first ALIVE token of
// the SAME half (same 8-load burst -> reliable MSHR merge); skip a half
// entirely (uniform branch) if it has no alive token.

constexpr int Bc = 16;
constexpr int Tc = 4096;
constexpr int Hc = 512;
constexpr int H4 = Hc / 4;             // 128 float4 per token
constexpr int CPB    = 128;            // chunk-columns per batch row
constexpr int NBLK   = Bc * CPB;       // 2048 stage-1 blocks
constexpr int ROWS_PB = CPB;           // 128 partial rows per b

// ---------------- stage 1 ----------------
// Block (b,c): 256 threads; lane = tid&127 (float4 column), par = tid>>7.
// Thread handles tokens t = 2c + par + 256k, k=0..15 (wave-uniform set).
__global__ __launch_bounds__(256) void glp_partial(
    const float* __restrict__ x,
    const int* __restrict__ lengths,
    const int* __restrict__ mask,   // int32 0/1
    float* __restrict__ pg,         // [NBLK][Hc]
    float* __restrict__ pl,         // [NBLK][Hc]
    int*   __restrict__ pcnt)       // [NBLK]
{
    const int blk  = blockIdx.x;
    const int b    = blk >> 7;              // / CPB
    const int c    = blk & (CPB - 1);
    const int lane = threadIdx.x & 127;
    const int par  = __builtin_amdgcn_readfirstlane(threadIdx.x >> 7); // scalar
    const int tbase = 2 * c + par;          // uniform per wave
    const int len  = lengths[b];

    const float4* __restrict__ xb =
        (const float4*)x + ((size_t)b * Tc + tbase) * H4 + lane;
    const int* __restrict__ mrow = mask + (size_t)b * Tc + tbase;  // uniform

    float4 g = make_float4(0.f, 0.f, 0.f, 0.f);
    float4 l = make_float4(0.f, 0.f, 0.f, 0.f);

    // all 16 mask words up front (wave-uniform scalar loads, lgkm pipe)
    int m[16];
    #pragma unroll
    for (int k = 0; k < 16; ++k) m[k] = mrow[k * 256];

    int mc = 0;
    #pragma unroll
    for (int k = 0; k < 16; ++k) mc += (m[k] != 0);

    #pragma unroll
    for (int half = 0; half < 2; ++half) {
        // scalar aliveness bitmap for this half's 8 tokens
        int ab = 0;
        #pragma unroll
        for (int j = 0; j < 8; ++j) {
            const int k = half * 8 + j;
            const int t = tbase + 256 * k;
            ab |= (((t < len) || (m[k] != 0)) ? 1 : 0) << j;
        }
        ab = __builtin_amdgcn_readfirstlane(ab);
        if (ab == 0) continue;               // wave-uniform: no alive token here
        const int fa = __ffs(ab) - 1;        // first alive j in this half

        float4 v[8];
        #pragma unroll
        for (int j = 0; j < 8; ++j) {
            const int k  = half * 8 + j;
            // dead -> clamp to this half's first alive token: its request is
            // in the SAME 8-load burst, still in flight -> MSHR merge.
            const int kc = ((ab >> j) & 1) ? k : (half * 8 + fa);
            v[j] = xb[(size_t)kc * 256 * H4];
        }
        #pragma unroll
        for (int j = 0; j < 8; ++j) {
            const int k = half * 8 + j;
            const int t = tbase + 256 * k;
            const float wg = (t < len) ? 1.f : 0.f;
            const float wl = m[k] ? 1.f : 0.f;
            g.x = fmaf(v[j].x, wg, g.x); g.y = fmaf(v[j].y, wg, g.y);
            g.z = fmaf(v[j].z, wg, g.z); g.w = fmaf(v[j].w, wg, g.w);
            l.x = fmaf(v[j].x, wl, l.x); l.y = fmaf(v[j].y, wl, l.y);
            l.z = fmaf(v[j].z, wl, l.z); l.w = fmaf(v[j].w, wl, l.w);
        }
    }

    // combine the two parities through LDS -> one partial row per block
    __shared__ float4 sg[128];
    __shared__ float4 sl[128];
    __shared__ int smc[2];
    if (par == 1) { sg[lane] = g; sl[lane] = l; }
    if (threadIdx.x == 0)   smc[0] = mc;   // mask uniform across a parity's lanes
    if (threadIdx.x == 128) smc[1] = mc;
    __syncthreads();
    if (par == 0) {
        const float4 og = sg[lane], ol = sl[lane];
        g.x += og.x; g.y += og.y; g.z += og.z; g.w += og.w;
        l.x += ol.x; l.y += ol.y; l.z += ol.z; l.w += ol.w;
        ((float4*)(pg + (size_t)blk * Hc))[lane] = g;   // 2 KB coalesced
        ((float4*)(pl + (size_t)blk * Hc))[lane] = l;
    }
    if (threadIdx.x == 0) pcnt[blk] = smc[0] + smc[1];
}

// ---------------- stage 2: 2048 rows -> out [B, 2H] ----------------
__global__ __launch_bounds__(128) void glp_reduce(
    const float* __restrict__ pg, const float* __restrict__ pl,
    const int* __restrict__ pcnt, const int* __restrict__ lengths,
    float* __restrict__ out)
{
    const int b   = blockIdx.x >> 3;
    const int o   = blockIdx.x & 7;
    const int col = o * 16 + (threadIdx.x & 15);   // float4 column in [0,128)
    const int rg  = threadIdx.x >> 4;              // 0..7

    const float4* pg4 = (const float4*)pg;
    const float4* pl4 = (const float4*)pl;

    float4 gs = make_float4(0.f, 0.f, 0.f, 0.f);
    float4 ls = make_float4(0.f, 0.f, 0.f, 0.f);
    #pragma unroll
    for (int half = 0; half < 2; ++half) {
        float4 a[8], d[8];
        #pragma unroll
        for (int j = 0; j < 8; ++j) {
            const int r = b * ROWS_PB + rg + 8 * (half * 8 + j);
            a[j] = pg4[(size_t)r * H4 + col];
            d[j] = pl4[(size_t)r * H4 + col];
        }
        #pragma unroll
        for (int j = 0; j < 8; ++j) {
            gs.x += a[j].x; gs.y += a[j].y; gs.z += a[j].z; gs.w += a[j].w;
            ls.x += d[j].x; ls.y += d[j].y; ls.z += d[j].z; ls.w += d[j].w;
        }
    }

    __shared__ float4 lg[128], ll[128];
    lg[threadIdx.x] = gs; ll[threadIdx.x] = ls;
    __syncthreads();
    if (rg == 0) {
        #pragma unroll
        for (int j = 1; j < 8; ++j) {
            const float4 a = lg[j * 16 + (threadIdx.x & 15)];
            const float4 d = ll[j * 16 + (threadIdx.x & 15)];
            gs.x += a.x; gs.y += a.y; gs.z += a.z; gs.w += a.w;
            ls.x += d.x; ls.y += d.y; ls.z += d.z; ls.w += d.w;
        }
        int cnt = 0;
        for (int i = 0; i < ROWS_PB; ++i) cnt += pcnt[b * ROWS_PB + i]; // uniform
        const float invl = 1.f / (float)max(lengths[b], 1);
        const float invc = 1.f / (float)max(cnt, 1);
        gs.x *= invl; gs.y *= invl; gs.z *= invl; gs.w *= invl;
        ls.x *= invc; ls.y *= invc; ls.z *= invc; ls.w *= invc;
        ((float4*)out)[b * 256 + col]       = gs;   // out row = 1024 floats
        ((float4*)out)[b * 256 + 128 + col] = ls;
    }
}

// ---------------- fallback (ws too small): proven atomic path ----------------
__global__ __launch_bounds__(128) void glp_partial_atomic(
    const float* __restrict__ x, const int* __restrict__ lengths,
    const int* __restrict__ mask,
    float* __restrict__ gsum, float* __restrict__ lsum, int* __restrict__ cnt)
{
    const int blk  = blockIdx.x;
    const int b    = blk >> 6;
    const int c    = blk & 63;
    const int t0   = c * 64;
    const int lane = threadIdx.x;
    const int len  = lengths[b];
    const float4* __restrict__ xb =
        (const float4*)x + ((size_t)b * Tc + t0) * H4 + lane;
    const int* __restrict__ mb = mask + (size_t)b * Tc + t0;

    float4 g = make_float4(0.f, 0.f, 0.f, 0.f);
    float4 l = make_float4(0.f, 0.f, 0.f, 0.f);
    int mc = 0;
    for (int ii = 0; ii < 64; ii += 8) {
        float4 v[8]; int m[8];
        #pragma unroll
        for (int j = 0; j < 8; ++j) { v[j] = xb[(size_t)(ii + j) * H4]; m[j] = mb[ii + j]; }
        #pragma unroll
        for (int j = 0; j < 8; ++j) {
            const float wg = (t0 + ii + j < len) ? 1.f : 0.f;
            const float wl = m[j] ? 1.f : 0.f;
            g.x = fmaf(v[j].x, wg, g.x); g.y = fmaf(v[j].y, wg, g.y);
            g.z = fmaf(v[j].z, wg, g.z); g.w = fmaf(v[j].w, wg, g.w);
            l.x = fmaf(v[j].x, wl, l.x); l.y = fmaf(v[j].y, wl, l.y);
            l.z = fmaf(v[j].z, wl, l.z); l.w = fmaf(v[j].w, wl, l.w);
            mc += (m[j] != 0);
        }
    }
    float* gp = gsum + b * Hc + lane * 4;
    float* lp = lsum + b * Hc + lane * 4;
    atomicAdd(gp + 0, g.x); atomicAdd(gp + 1, g.y);
    atomicAdd(gp + 2, g.z); atomicAdd(gp + 3, g.w);
    atomicAdd(lp + 0, l.x); atomicAdd(lp + 1, l.y);
    atomicAdd(lp + 2, l.z); atomicAdd(lp + 3, l.w);
    if (lane == 0) atomicAdd(cnt + b, mc);
}

__global__ __launch_bounds__(512) void glp_finalize(
    const float* __restrict__ gsum, const float* __restrict__ lsum,
    const int* __restrict__ cnt, const int* __restrict__ lengths,
    float* __restrict__ out)
{
    const int b = blockIdx.x;
    const int h = threadIdx.x;
    out[b * 2 * Hc + h]      = gsum[b * Hc + h] / (float)max(lengths[b], 1);
    out[b * 2 * Hc + Hc + h] = lsum[b * Hc + h] / (float)max(cnt[b], 1);
}

extern "C" void kernel_launch(void* const* d_in, const int* in_sizes, int n_in,
                              void* d_out, int out_size, void* d_ws, size_t ws_size,
                              hipStream_t stream) {
    const float* x     = (const float*)d_in[0];
    const int* lengths = (const int*)d_in[1];
    const int* mask    = (const int*)d_in[2];   // bool promoted to int32 by harness
    float* out = (float*)d_out;

    const size_t npg  = (size_t)NBLK * Hc;  // floats per partial array
    const size_t need = 2 * npg * sizeof(float) + NBLK * sizeof(int);
    if (ws_size >= need) {
        float* pg   = (float*)d_ws;
        float* pl   = pg + npg;
        int*   pcnt = (int*)(pl + npg);
        glp_partial<<<NBLK, 256, 0, stream>>>(x, lengths, mask, pg, pl, pcnt);
        glp_reduce<<<Bc * 8, 128, 0, stream>>>(pg, pl, pcnt, lengths, out);
    } else {
        float* gsum = (float*)d_ws;
        float* lsum = gsum + Bc * Hc;
        int*   cnt  = (int*)(lsum + Bc * Hc);
        const size_t zb = (size_t)(2 * Bc * Hc) * sizeof(float) + Bc * sizeof(int);
        hipMemsetAsync(d_ws, 0, zb, stream);
        glp_partial_atomic<<<Bc * 64, 128, 0, stream>>>(x, lengths, mask, gsum, lsum, cnt);
        glp_finalize<<<Bc, Hc, 0, stream>>>(gsum, lsum, cnt, lengths, out);
    }
}